// Round 1
// baseline (17641.052 us; speedup 1.0000x reference)
//
#include <hip/hip_runtime.h>
#include <math.h>

#define B_N 32
#define T_N 1024
#define E_N 512
#define H_N 512
#define G4_N 2048  // 4*H

typedef __attribute__((ext_vector_type(8))) short short8;
typedef __attribute__((ext_vector_type(4))) float f32x4;

__device__ __forceinline__ unsigned short f2bfu(float f) {
  unsigned int x = __builtin_bit_cast(unsigned int, f);
  x += 0x7fffu + ((x >> 16) & 1u);
  return (unsigned short)(x >> 16);
}
__device__ __forceinline__ float bfu2f(unsigned short u) {
  return __builtin_bit_cast(float, ((unsigned int)u) << 16);
}
__device__ __forceinline__ float sigmf(float x) { return 1.0f / (1.0f + expf(-x)); }

// ---------------------------------------------------------------------------
// Kernel 1: xw[dir][t_local][g][b] (bf16) = dot(W_ih[dir][g,:], X[dir][(t,b),:]) + bias[g]
// X row for bwd is the length-reversed xs row (matches reference idx).
// Tile 64(g) x 64(n=t*32+b), BK=64, 4 waves 2x2, 16x16x32 bf16 MFMA.
// ---------------------------------------------------------------------------
__global__ __launch_bounds__(256) void xw_gemm_kernel(
    const float* __restrict__ xs, const int* __restrict__ lengths,
    const float* __restrict__ w_ih_f, const float* __restrict__ b_f,
    const float* __restrict__ w_ih_b, const float* __restrict__ b_b,
    unsigned short* __restrict__ xw, int t0, int Tseg)
{
  __shared__ unsigned short As[64][80];  // stride 160B: 16B aligned rows
  __shared__ unsigned short Bs[64][80];
  const int g0 = blockIdx.x * 64;
  const int n0 = blockIdx.y * 64;
  const int dir = blockIdx.z;
  const float* __restrict__ W = dir ? w_ih_b : w_ih_f;
  const float* __restrict__ bias = dir ? b_b : b_f;
  const int tid = threadIdx.x;
  const int w = tid >> 6, lane = tid & 63;
  const int wr = w >> 1, wc = w & 1;

  // staging assignment: 4 threads per row, 16 floats each
  const int sr = tid >> 2;
  const int sq = tid & 3;
  const int nrow = n0 + sr;
  const int bb = nrow & 31;
  const int tt = t0 + (nrow >> 5);
  const int Lb = lengths[bb];
  const int src_t = (dir != 0 && tt < Lb) ? (Lb - 1 - tt) : tt;
  const float* __restrict__ xrow = xs + ((size_t)bb * T_N + src_t) * E_N;
  const float* __restrict__ arow = W + (size_t)(g0 + sr) * E_N;

  f32x4 acc[2][2] = {};

  for (int k0 = 0; k0 < E_N; k0 += 64) {
    float4 av[4], bv[4];
#pragma unroll
    for (int i = 0; i < 4; ++i) {
      av[i] = *(const float4*)&arow[k0 + sq * 16 + i * 4];
      bv[i] = *(const float4*)&xrow[k0 + sq * 16 + i * 4];
    }
    __syncthreads();  // protect previous iteration's fragment reads
#pragma unroll
    for (int i = 0; i < 4; ++i) {
      ushort4 a4, b4;
      a4.x = f2bfu(av[i].x); a4.y = f2bfu(av[i].y); a4.z = f2bfu(av[i].z); a4.w = f2bfu(av[i].w);
      b4.x = f2bfu(bv[i].x); b4.y = f2bfu(bv[i].y); b4.z = f2bfu(bv[i].z); b4.w = f2bfu(bv[i].w);
      *(ushort4*)&As[sr][sq * 16 + i * 4] = a4;
      *(ushort4*)&Bs[sr][sq * 16 + i * 4] = b4;
    }
    __syncthreads();
#pragma unroll
    for (int kk = 0; kk < 2; ++kk) {
      const int ko = kk * 32 + ((lane >> 4) << 3);
      short8 bf0 = *(const short8*)&Bs[wc * 32 + (lane & 15)][ko];
      short8 bf1 = *(const short8*)&Bs[wc * 32 + 16 + (lane & 15)][ko];
      short8 af0 = *(const short8*)&As[wr * 32 + (lane & 15)][ko];
      short8 af1 = *(const short8*)&As[wr * 32 + 16 + (lane & 15)][ko];
      acc[0][0] = __builtin_amdgcn_mfma_f32_16x16x32_bf16(af0, bf0, acc[0][0], 0, 0, 0);
      acc[0][1] = __builtin_amdgcn_mfma_f32_16x16x32_bf16(af0, bf1, acc[0][1], 0, 0, 0);
      acc[1][0] = __builtin_amdgcn_mfma_f32_16x16x32_bf16(af1, bf0, acc[1][0], 0, 0, 0);
      acc[1][1] = __builtin_amdgcn_mfma_f32_16x16x32_bf16(af1, bf1, acc[1][1], 0, 0, 0);
    }
  }

  // C/D layout: col = lane&15 (n side), row = (lane>>4)*4+j (m side)
#pragma unroll
  for (int mt = 0; mt < 2; ++mt)
#pragma unroll
    for (int nt = 0; nt < 2; ++nt)
#pragma unroll
      for (int j = 0; j < 4; ++j) {
        const int m = g0 + wr * 32 + mt * 16 + ((lane >> 4) << 2) + j;
        const int n = n0 + wc * 32 + nt * 16 + (lane & 15);
        const int tl = n >> 5, b = n & 31;
        const float v = acc[mt][nt][j] + bias[m];
        xw[(((size_t)dir * Tseg + tl) * G4_N + m) * B_N + b] = f2bfu(v);
      }
}

// ---------------------------------------------------------------------------
// Kernel 2: persistent recurrence. 64 wgs (dir = wg&1, colgroup = wg>>1 of 32).
// Each wg owns 16 h-cols = 64 gate rows; W_hh slice LDS-resident (bf16).
// Per step: barrier-wait -> stage h (global->LDS) + xw slice -> MFMA gates ->
// gate nonlinearity (fp32, c in regs) -> write h (bf16) + logits partial ->
// fence -> arrive. Counter-accumulate barrier, agent scope.
// ---------------------------------------------------------------------------
__global__ __launch_bounds__(256, 1) void rec_kernel(
    const unsigned short* __restrict__ xw,
    const float* __restrict__ w_hh_f, const float* __restrict__ w_hh_b,
    const float* __restrict__ w_cls, const int* __restrict__ lengths,
    unsigned short* __restrict__ h_buf,   // [2][2][B][H] bf16
    float* __restrict__ c_buf,            // [2][B][H]
    float* __restrict__ logits,           // [B][T][2]
    unsigned int* __restrict__ ctrs,      // this segment's counters, [dir*16]
    int t0, int Tseg)
{
  __shared__ unsigned short Ws[64][520];   // 66.5 KB, row stride 1040B (16B-mult)
  __shared__ unsigned short Ah[32][520];   // 33.3 KB
  __shared__ unsigned short xw_s[4][16][32];
  __shared__ float gate_s[4][32][16];      // [gate q][b][col-local]
  __shared__ float lp[8][32][2];           // logits partials

  const int tid = threadIdx.x;
  const int wg = blockIdx.x;
  const int dir = wg & 1;
  const int cg = wg >> 1;
  const int colbase = cg * 16;
  const float* __restrict__ w_hh = dir ? w_hh_b : w_hh_f;

  // one-time: stage W_hh slice, rows ordered [q][cl] (q=gate i,f,g,o)
  for (int i = tid; i < 64 * 128; i += 256) {
    const int r = i >> 7;
    const int k4 = (i & 127) << 2;
    const int q = r >> 4, cl = r & 15;
    const int grow = q * 512 + colbase + cl;
    const float4 v = *(const float4*)&w_hh[(size_t)grow * H_N + k4];
    ushort4 u;
    u.x = f2bfu(v.x); u.y = f2bfu(v.y); u.z = f2bfu(v.z); u.w = f2bfu(v.w);
    *(ushort4*)&Ws[r][k4] = u;
  }

  // per-thread epilogue ownership: (b, 2 cols)
  const int b = tid & 31;
  const int c2 = tid >> 5;  // 0..7
  const int cl0 = c2 * 2, cl1 = cl0 + 1;
  const int col0 = colbase + cl0, col1 = colbase + cl1;
  const int Lb = lengths[b];
  float cc0 = c_buf[((size_t)dir * B_N + b) * H_N + col0];
  float cc1 = c_buf[((size_t)dir * B_N + b) * H_N + col1];
  float hh0 = bfu2f(h_buf[(((size_t)dir * 2 + (t0 & 1)) * B_N + b) * H_N + col0]);
  float hh1 = bfu2f(h_buf[(((size_t)dir * 2 + (t0 & 1)) * B_N + b) * H_N + col1]);
  const float wc00 = w_cls[0 * (2 * H_N) + dir * H_N + col0];
  const float wc01 = w_cls[0 * (2 * H_N) + dir * H_N + col1];
  const float wc10 = w_cls[1 * (2 * H_N) + dir * H_N + col0];
  const float wc11 = w_cls[1 * (2 * H_N) + dir * H_N + col1];

  const int w = tid >> 6;
  const int lane = tid & 63;
  unsigned int* ctr = &ctrs[dir * 16];

  for (int ts = 0; ts < Tseg; ++ts) {
    const int t = t0 + ts;
    const int cur = t & 1, nxt = cur ^ 1;

    if (ts > 0) {
      if (tid == 0) {
        const unsigned int target = 32u * (unsigned int)ts;
        while (__hip_atomic_load(ctr, __ATOMIC_ACQUIRE, __HIP_MEMORY_SCOPE_AGENT) < target)
          __builtin_amdgcn_s_sleep(2);
      }
      __syncthreads();
      __threadfence();  // acquire side: make remote h writes visible to all threads
    }

    // stage h (bf16, coalesced) into Ah
    {
      const unsigned short* __restrict__ hsrc = &h_buf[(((size_t)dir * 2 + cur) * B_N) * H_N];
      for (int i = tid; i < 32 * 64; i += 256) {
        const int r = i >> 6, k8 = (i & 63) << 3;
        const uint4 v = *(const uint4*)&hsrc[(size_t)r * H_N + k8];
        *(uint4*)&Ah[r][k8] = v;
      }
      // stage this wg's xw slice [4 gates][16 cols][32 b]
      const int q = tid >> 6, cl = (tid >> 2) & 15, b0 = (tid & 3) << 3;
      const uint4 v = *(const uint4*)&xw[(((size_t)dir * Tseg + ts) * G4_N + q * 512 + colbase + cl) * B_N + b0];
      *(uint4*)&xw_s[q][cl][b0] = v;
    }
    __syncthreads();

    // MFMA: gates[b][n] = sum_k h[b][k] * Whh[grow(n)][k]; wave w handles gate q=w
    {
      f32x4 acc0 = {0.f, 0.f, 0.f, 0.f}, acc1 = {0.f, 0.f, 0.f, 0.f};
      const int br = (w << 4) + (lane & 15);
      const int kb = (lane >> 4) << 3;
#pragma unroll
      for (int ks = 0; ks < 16; ++ks) {
        const int kk = (ks << 5) + kb;
        short8 bf = *(const short8*)&Ws[br][kk];
        short8 a0 = *(const short8*)&Ah[(lane & 15)][kk];
        short8 a1 = *(const short8*)&Ah[16 + (lane & 15)][kk];
        acc0 = __builtin_amdgcn_mfma_f32_16x16x32_bf16(a0, bf, acc0, 0, 0, 0);
        acc1 = __builtin_amdgcn_mfma_f32_16x16x32_bf16(a1, bf, acc1, 0, 0, 0);
      }
      const int crow = (lane >> 4) << 2;
      const int ccol = lane & 15;
#pragma unroll
      for (int j = 0; j < 4; ++j) {
        gate_s[w][crow + j][ccol] = acc0[j];
        gate_s[w][16 + crow + j][ccol] = acc1[j];
      }
    }
    __syncthreads();

    // epilogue: gate nonlinearity + state update (fp32)
    const bool valid = (t < Lb);
    float hn0, hn1;
    {
      float gi = gate_s[0][b][cl0] + bfu2f(xw_s[0][cl0][b]);
      float gf = gate_s[1][b][cl0] + bfu2f(xw_s[1][cl0][b]);
      float gg = gate_s[2][b][cl0] + bfu2f(xw_s[2][cl0][b]);
      float go = gate_s[3][b][cl0] + bfu2f(xw_s[3][cl0][b]);
      float cn = sigmf(gf) * cc0 + sigmf(gi) * tanhf(gg);
      hn0 = sigmf(go) * tanhf(cn);
      if (valid) { cc0 = cn; hh0 = hn0; }

      gi = gate_s[0][b][cl1] + bfu2f(xw_s[0][cl1][b]);
      gf = gate_s[1][b][cl1] + bfu2f(xw_s[1][cl1][b]);
      gg = gate_s[2][b][cl1] + bfu2f(xw_s[2][cl1][b]);
      go = gate_s[3][b][cl1] + bfu2f(xw_s[3][cl1][b]);
      cn = sigmf(gf) * cc1 + sigmf(gi) * tanhf(gg);
      hn1 = sigmf(go) * tanhf(cn);
      if (valid) { cc1 = cn; hh1 = hn1; }
    }
    // write h (frozen value when masked) to the next-parity buffer
    {
      unsigned short* __restrict__ hdst = &h_buf[(((size_t)dir * 2 + nxt) * B_N + b) * H_N];
      hdst[col0] = f2bfu(hh0);
      hdst[col1] = f2bfu(hh1);
    }
    // logits partials (h_new * mask dotted with w_cls slice)
    lp[c2][b][0] = valid ? (hn0 * wc00 + hn1 * wc01) : 0.f;
    lp[c2][b][1] = valid ? (hn0 * wc10 + hn1 * wc11) : 0.f;

    __threadfence();   // order h_buf stores before the arrive
    __syncthreads();   // all threads fenced + lp visible
    if (tid == 0)
      __hip_atomic_fetch_add(ctr, 1u, __ATOMIC_RELEASE, __HIP_MEMORY_SCOPE_AGENT);

    // off-critical-path: reduce + accumulate logits
    if (tid < 64) {
      const int tau = tid >> 5;
      float s = 0.f;
#pragma unroll
      for (int k = 0; k < 8; ++k) s += lp[k][b][tau];
      if (t < Lb) {
        const int tpos = dir ? (Lb - 1 - t) : t;
        atomicAdd(&logits[((size_t)b * T_N + tpos) * 2 + tau], s);
      }
    }
  }

  // persist c across segment launches (h persists via h_buf)
  c_buf[((size_t)dir * B_N + b) * H_N + col0] = cc0;
  c_buf[((size_t)dir * B_N + b) * H_N + col1] = cc1;
}

// ---------------------------------------------------------------------------
__global__ void init_kernel(unsigned short* __restrict__ h_buf, float* __restrict__ c_buf,
                            float* __restrict__ logits, unsigned int* __restrict__ ctrs,
                            const float* __restrict__ b_cls)
{
  const int i = blockIdx.x * 256 + threadIdx.x;  // 0..65535
  if (i < 2 * 2 * B_N * H_N) h_buf[i] = 0;
  if (i < 2 * B_N * H_N) c_buf[i] = 0.f;
  if (i < B_N * T_N * 2) logits[i] = b_cls[i & 1];  // padded positions -> softmax(b_cls)
  if (i < 2048) ctrs[i] = 0;
}

__global__ void softmax_kernel(const float* __restrict__ logits, float* __restrict__ out)
{
  const int i = blockIdx.x * 256 + threadIdx.x;  // 0..32767
  if (i < B_N * T_N) {
    const float l0 = logits[2 * i], l1 = logits[2 * i + 1];
    const float m = fmaxf(l0, l1);
    const float e0 = expf(l0 - m), e1 = expf(l1 - m);
    const float inv = 1.f / (e0 + e1);
    out[2 * i] = e0 * inv;
    out[2 * i + 1] = e1 * inv;
  }
}

// ---------------------------------------------------------------------------
extern "C" void kernel_launch(void* const* d_in, const int* in_sizes, int n_in,
                              void* d_out, int out_size, void* d_ws, size_t ws_size,
                              hipStream_t stream)
{
  const float* xs      = (const float*)d_in[0];
  const int*   lengths = (const int*)d_in[1];
  // d_in[2] domains: unused (single-domain path)
  const float* w_ih_f  = (const float*)d_in[3];
  const float* w_hh_f  = (const float*)d_in[4];
  const float* b_f     = (const float*)d_in[5];
  const float* w_ih_b  = (const float*)d_in[6];
  const float* w_hh_b  = (const float*)d_in[7];
  const float* b_b     = (const float*)d_in[8];
  const float* w_cls   = (const float*)d_in[9];
  const float* b_cls   = (const float*)d_in[10];
  float* out = (float*)d_out;

  auto alignup = [](size_t v) { return (v + 255) & ~(size_t)255; };
  const size_t hbuf_b = alignup((size_t)2 * 2 * B_N * H_N * 2);
  const size_t cbuf_b = alignup((size_t)2 * B_N * H_N * 4);
  const size_t logit_b = alignup((size_t)B_N * T_N * 2 * 4);
  const size_t ctr_b = alignup((size_t)64 * 32 * 4);
  const size_t fixed = hbuf_b + cbuf_b + logit_b + ctr_b + 1024;

  // pick the fewest segments whose xw buffer fits the workspace
  int nseg = 1;
  while (nseg < 64) {
    const size_t xwb = alignup((size_t)2 * (T_N / nseg) * G4_N * B_N * 2);
    if (xwb + fixed <= ws_size) break;
    nseg <<= 1;
  }
  const int Tseg = T_N / nseg;
  const size_t xw_b = alignup((size_t)2 * Tseg * G4_N * B_N * 2);

  char* p = (char*)d_ws;
  unsigned short* xw = (unsigned short*)p;      p += xw_b;
  unsigned short* h_buf = (unsigned short*)p;   p += hbuf_b;
  float* c_buf = (float*)p;                     p += cbuf_b;
  float* logits = (float*)p;                    p += logit_b;
  unsigned int* ctrs = (unsigned int*)p;        p += ctr_b;

  init_kernel<<<256, 256, 0, stream>>>(h_buf, c_buf, logits, ctrs, b_cls);

  for (int s = 0; s < nseg; ++s) {
    const int t0 = s * Tseg;
    dim3 g(G4_N / 64, (Tseg * B_N) / 64, 2);
    xw_gemm_kernel<<<g, 256, 0, stream>>>(xs, lengths, w_ih_f, b_f, w_ih_b, b_b, xw, t0, Tseg);
    rec_kernel<<<64, 256, 0, stream>>>(xw, w_hh_f, w_hh_b, w_cls, lengths,
                                       h_buf, c_buf, logits, ctrs + s * 32, t0, Tseg);
  }

  softmax_kernel<<<128, 256, 0, stream>>>(logits, out);
}

// Round 2
// 7984.528 us; speedup vs baseline: 2.2094x; 2.2094x over previous
//
#include <hip/hip_runtime.h>
#include <math.h>

#define B_N 32
#define T_N 1024
#define E_N 512
#define H_N 512
#define G4_N 2048  // 4*H

typedef __attribute__((ext_vector_type(8))) short short8;
typedef __attribute__((ext_vector_type(4))) float f32x4;

__device__ __forceinline__ unsigned short f2bfu(float f) {
  unsigned int x = __builtin_bit_cast(unsigned int, f);
  x += 0x7fffu + ((x >> 16) & 1u);
  return (unsigned short)(x >> 16);
}
__device__ __forceinline__ float bfu2f(unsigned short u) {
  return __builtin_bit_cast(float, ((unsigned int)u) << 16);
}
__device__ __forceinline__ float sigmf(float x) { return 1.0f / (1.0f + expf(-x)); }

// ---------------------------------------------------------------------------
// Kernel 1 (unchanged): xw[dir][t_local][g][b] bf16 = W_ih[dir] @ x(+rev) + b
// ---------------------------------------------------------------------------
__global__ __launch_bounds__(256) void xw_gemm_kernel(
    const float* __restrict__ xs, const int* __restrict__ lengths,
    const float* __restrict__ w_ih_f, const float* __restrict__ b_f,
    const float* __restrict__ w_ih_b, const float* __restrict__ b_b,
    unsigned short* __restrict__ xw, int t0, int Tseg)
{
  __shared__ unsigned short As[64][80];
  __shared__ unsigned short Bs[64][80];
  const int g0 = blockIdx.x * 64;
  const int n0 = blockIdx.y * 64;
  const int dir = blockIdx.z;
  const float* __restrict__ W = dir ? w_ih_b : w_ih_f;
  const float* __restrict__ bias = dir ? b_b : b_f;
  const int tid = threadIdx.x;
  const int w = tid >> 6, lane = tid & 63;
  const int wr = w >> 1, wc = w & 1;

  const int sr = tid >> 2;
  const int sq = tid & 3;
  const int nrow = n0 + sr;
  const int bb = nrow & 31;
  const int tt = t0 + (nrow >> 5);
  const int Lb = lengths[bb];
  const int src_t = (dir != 0 && tt < Lb) ? (Lb - 1 - tt) : tt;
  const float* __restrict__ xrow = xs + ((size_t)bb * T_N + src_t) * E_N;
  const float* __restrict__ arow = W + (size_t)(g0 + sr) * E_N;

  f32x4 acc[2][2] = {};

  for (int k0 = 0; k0 < E_N; k0 += 64) {
    float4 av[4], bv[4];
#pragma unroll
    for (int i = 0; i < 4; ++i) {
      av[i] = *(const float4*)&arow[k0 + sq * 16 + i * 4];
      bv[i] = *(const float4*)&xrow[k0 + sq * 16 + i * 4];
    }
    __syncthreads();
#pragma unroll
    for (int i = 0; i < 4; ++i) {
      ushort4 a4, b4;
      a4.x = f2bfu(av[i].x); a4.y = f2bfu(av[i].y); a4.z = f2bfu(av[i].z); a4.w = f2bfu(av[i].w);
      b4.x = f2bfu(bv[i].x); b4.y = f2bfu(bv[i].y); b4.z = f2bfu(bv[i].z); b4.w = f2bfu(bv[i].w);
      *(ushort4*)&As[sr][sq * 16 + i * 4] = a4;
      *(ushort4*)&Bs[sr][sq * 16 + i * 4] = b4;
    }
    __syncthreads();
#pragma unroll
    for (int kk = 0; kk < 2; ++kk) {
      const int ko = kk * 32 + ((lane >> 4) << 3);
      short8 bf0 = *(const short8*)&Bs[wc * 32 + (lane & 15)][ko];
      short8 bf1 = *(const short8*)&Bs[wc * 32 + 16 + (lane & 15)][ko];
      short8 af0 = *(const short8*)&As[wr * 32 + (lane & 15)][ko];
      short8 af1 = *(const short8*)&As[wr * 32 + 16 + (lane & 15)][ko];
      acc[0][0] = __builtin_amdgcn_mfma_f32_16x16x32_bf16(af0, bf0, acc[0][0], 0, 0, 0);
      acc[0][1] = __builtin_amdgcn_mfma_f32_16x16x32_bf16(af0, bf1, acc[0][1], 0, 0, 0);
      acc[1][0] = __builtin_amdgcn_mfma_f32_16x16x32_bf16(af1, bf0, acc[1][0], 0, 0, 0);
      acc[1][1] = __builtin_amdgcn_mfma_f32_16x16x32_bf16(af1, bf1, acc[1][1], 0, 0, 0);
    }
  }

#pragma unroll
  for (int mt = 0; mt < 2; ++mt)
#pragma unroll
    for (int nt = 0; nt < 2; ++nt)
#pragma unroll
      for (int j = 0; j < 4; ++j) {
        const int m = g0 + wr * 32 + mt * 16 + ((lane >> 4) << 2) + j;
        const int n = n0 + wc * 32 + nt * 16 + (lane & 15);
        const int tl = n >> 5, b = n & 31;
        const float v = acc[mt][nt][j] + bias[m];
        xw[(((size_t)dir * Tseg + tl) * G4_N + m) * B_N + b] = f2bfu(v);
      }
}

// ---------------------------------------------------------------------------
// Kernel 2: persistent recurrence, fence-free coherent h exchange.
// h_buf layout: [dir][parity][p=32 producers][b=32][cl=16] bf16 — each
// producer's slice is a contiguous 1KB block.  All h_buf traffic inside the
// loop uses relaxed agent-scope atomics (coherent point, no L1/L2 staleness,
// no buffer_inv/wbl2).  Flags are monotonic step counters, one per producer.
// ---------------------------------------------------------------------------
__global__ __launch_bounds__(256, 1) void rec_kernel(
    const unsigned short* __restrict__ xw,
    const float* __restrict__ w_hh_f, const float* __restrict__ w_hh_b,
    const float* __restrict__ w_cls, const int* __restrict__ lengths,
    unsigned short* __restrict__ h_buf,   // [2][2][32][32][16] bf16
    float* __restrict__ c_buf,            // [2][B][H]
    float* __restrict__ lpart,            // [64 wg][B][T][2] private partials
    unsigned int* __restrict__ flags,     // this segment: [2][32]
    int t0, int Tseg)
{
  __shared__ unsigned short Ws[64][520];   // 66.5 KB
  __shared__ unsigned short Ah[32][520];   // 33.3 KB
  __shared__ unsigned short xw_s[4][16][32];
  __shared__ float gate_s[4][32][16];
  __shared__ float lp[8][32][2];

  const int tid = threadIdx.x;
  const int wg = blockIdx.x;
  const int dir = wg & 1;
  const int cg = wg >> 1;
  const int colbase = cg * 16;
  const float* __restrict__ w_hh = dir ? w_hh_b : w_hh_f;

  // one-time: stage W_hh slice, rows ordered [q][cl]
  for (int i = tid; i < 64 * 128; i += 256) {
    const int r = i >> 7;
    const int k4 = (i & 127) << 2;
    const int q = r >> 4, cl = r & 15;
    const int grow = q * 512 + colbase + cl;
    const float4 v = *(const float4*)&w_hh[(size_t)grow * H_N + k4];
    ushort4 u;
    u.x = f2bfu(v.x); u.y = f2bfu(v.y); u.z = f2bfu(v.z); u.w = f2bfu(v.w);
    *(ushort4*)&Ws[r][k4] = u;
  }

  const int b = tid & 31;
  const int c2 = tid >> 5;              // 0..7
  const int cl0 = c2 * 2, cl1 = cl0 + 1;
  const int col0 = colbase + cl0, col1 = colbase + cl1;
  const int Lb = lengths[b];
  const int p0 = t0 & 1;
  float cc0 = c_buf[((size_t)dir * B_N + b) * H_N + col0];
  float cc1 = c_buf[((size_t)dir * B_N + b) * H_N + col1];
  float hh0 = bfu2f(h_buf[((((size_t)dir * 2 + p0) * 32 + cg) * 32 + b) * 16 + cl0]);
  float hh1 = bfu2f(h_buf[((((size_t)dir * 2 + p0) * 32 + cg) * 32 + b) * 16 + cl1]);
  const float wc00 = w_cls[0 * (2 * H_N) + dir * H_N + col0];
  const float wc01 = w_cls[0 * (2 * H_N) + dir * H_N + col1];
  const float wc10 = w_cls[1 * (2 * H_N) + dir * H_N + col0];
  const float wc11 = w_cls[1 * (2 * H_N) + dir * H_N + col1];

  const int w = tid >> 6;
  const int lane = tid & 63;
  unsigned int* __restrict__ dflags = flags + dir * 32;
  float* __restrict__ lslice = lpart + (size_t)wg * B_N * T_N * 2;

  for (int ts = 0; ts < Tseg; ++ts) {
    const int t = t0 + ts;
    const int cur = t & 1, nxt = cur ^ 1;

    // wait for all 32 producers of this dir to have published step ts's input
    if (ts > 0 && lane < 32) {
      const unsigned int tgt = (unsigned int)ts;
      unsigned int* f = &dflags[lane];
      while (__hip_atomic_load(f, __ATOMIC_RELAXED, __HIP_MEMORY_SCOPE_AGENT) < tgt)
        __builtin_amdgcn_s_sleep(1);
    }

    // restage full h via coherent loads (bypass stale caches)
    {
      const unsigned long long* __restrict__ hsrc =
          (const unsigned long long*)&h_buf[((size_t)dir * 2 + cur) * (32 * 32 * 16)];
#pragma unroll
      for (int j = 0; j < 16; ++j) {
        const int i = tid + j * 256;
        const int p = i >> 7, r = i & 127;
        const int bb2 = r >> 2, c4 = (r & 3) * 4;
        unsigned long long v = __hip_atomic_load(&hsrc[(p * 32 + bb2) * 4 + (c4 >> 2)],
                                                 __ATOMIC_RELAXED, __HIP_MEMORY_SCOPE_AGENT);
        *(unsigned long long*)&Ah[bb2][p * 16 + c4] = v;
      }
      // stage this wg's xw slice (normally cached; written by prior dispatch)
      const int q = tid >> 6, cl = (tid >> 2) & 15, b0 = (tid & 3) << 3;
      const uint4 v = *(const uint4*)&xw[(((size_t)dir * Tseg + ts) * G4_N + q * 512 + colbase + cl) * B_N + b0];
      *(uint4*)&xw_s[q][cl][b0] = v;
    }
    __syncthreads();  // SYNC1: Ah/xw_s (and first-iter Ws) ready

    // MFMA: gates[b][n] ; wave w handles gate q=w (16 of this wg's 64 rows)
    {
      f32x4 acc0 = {0.f, 0.f, 0.f, 0.f}, acc1 = {0.f, 0.f, 0.f, 0.f};
      const int br = (w << 4) + (lane & 15);
      const int kb = (lane >> 4) << 3;
#pragma unroll
      for (int ks = 0; ks < 16; ++ks) {
        const int kk = (ks << 5) + kb;
        short8 bf = *(const short8*)&Ws[br][kk];
        short8 a0 = *(const short8*)&Ah[(lane & 15)][kk];
        short8 a1 = *(const short8*)&Ah[16 + (lane & 15)][kk];
        acc0 = __builtin_amdgcn_mfma_f32_16x16x32_bf16(a0, bf, acc0, 0, 0, 0);
        acc1 = __builtin_amdgcn_mfma_f32_16x16x32_bf16(a1, bf, acc1, 0, 0, 0);
      }
      const int crow = (lane >> 4) << 2;
      const int ccol = lane & 15;
#pragma unroll
      for (int j = 0; j < 4; ++j) {
        gate_s[w][crow + j][ccol] = acc0[j];
        gate_s[w][16 + crow + j][ccol] = acc1[j];
      }
    }
    __syncthreads();  // SYNC2: gate_s ready

    // epilogue: gate nonlinearity + state update (fp32)
    const bool valid = (t < Lb);
    float hn0, hn1;
    {
      float gi = gate_s[0][b][cl0] + bfu2f(xw_s[0][cl0][b]);
      float gf = gate_s[1][b][cl0] + bfu2f(xw_s[1][cl0][b]);
      float gg = gate_s[2][b][cl0] + bfu2f(xw_s[2][cl0][b]);
      float go = gate_s[3][b][cl0] + bfu2f(xw_s[3][cl0][b]);
      float cn = sigmf(gf) * cc0 + sigmf(gi) * tanhf(gg);
      hn0 = sigmf(go) * tanhf(cn);
      if (valid) { cc0 = cn; hh0 = hn0; }

      gi = gate_s[0][b][cl1] + bfu2f(xw_s[0][cl1][b]);
      gf = gate_s[1][b][cl1] + bfu2f(xw_s[1][cl1][b]);
      gg = gate_s[2][b][cl1] + bfu2f(xw_s[2][cl1][b]);
      go = gate_s[3][b][cl1] + bfu2f(xw_s[3][cl1][b]);
      cn = sigmf(gf) * cc1 + sigmf(gi) * tanhf(gg);
      hn1 = sigmf(go) * tanhf(cn);
      if (valid) { cc1 = cn; hh1 = hn1; }
    }

    // publish h slice (coherent store; 1KB contiguous block per producer)
    {
      unsigned int hv = (unsigned int)f2bfu(hh0) | ((unsigned int)f2bfu(hh1) << 16);
      unsigned int* hdst = (unsigned int*)h_buf +
          ((size_t)dir * 2 + nxt) * 8192 + (cg * 32 + b) * 8 + c2;
      __hip_atomic_store(hdst, hv, __ATOMIC_RELAXED, __HIP_MEMORY_SCOPE_AGENT);
    }
    lp[c2][b][0] = valid ? (hn0 * wc00 + hn1 * wc01) : 0.f;
    lp[c2][b][1] = valid ? (hn0 * wc10 + hn1 * wc11) : 0.f;

    asm volatile("s_waitcnt vmcnt(0)" ::: "memory");  // h stores at coherent point
    __syncthreads();  // SYNC3: all waves' stores drained, lp visible

    if (tid == 0)
      __hip_atomic_store(&dflags[cg], (unsigned int)(ts + 1),
                         __ATOMIC_RELAXED, __HIP_MEMORY_SCOPE_AGENT);

    // off-critical-path: private logits partial (plain cached store, no atomics)
    if (tid < 32) {
      float s0 = 0.f, s1 = 0.f;
#pragma unroll
      for (int k = 0; k < 8; ++k) { s0 += lp[k][b][0]; s1 += lp[k][b][1]; }
      if (t < Lb) {
        const int tpos = dir ? (Lb - 1 - t) : t;
        float2 v; v.x = s0; v.y = s1;
        *(float2*)&lslice[((size_t)b * T_N + tpos) * 2] = v;
      }
    }
  }

  // persist c across segment launches (h persists via h_buf)
  c_buf[((size_t)dir * B_N + b) * H_N + col0] = cc0;
  c_buf[((size_t)dir * B_N + b) * H_N + col1] = cc1;
}

// ---------------------------------------------------------------------------
__global__ void reduce_softmax_kernel(const float* __restrict__ lpart,
                                      const float* __restrict__ b_cls,
                                      float* __restrict__ out)
{
  const int i = blockIdx.x * 256 + threadIdx.x;  // 0..32767
  if (i >= B_N * T_N) return;
  float s0 = b_cls[0], s1 = b_cls[1];
  const float* __restrict__ p = lpart + (size_t)i * 2;
#pragma unroll 8
  for (int wg = 0; wg < 64; ++wg) {
    s0 += p[(size_t)wg * B_N * T_N * 2];
    s1 += p[(size_t)wg * B_N * T_N * 2 + 1];
  }
  const float m = fmaxf(s0, s1);
  const float e0 = expf(s0 - m), e1 = expf(s1 - m);
  const float inv = 1.f / (e0 + e1);
  out[2 * i] = e0 * inv;
  out[2 * i + 1] = e1 * inv;
}

// ---------------------------------------------------------------------------
extern "C" void kernel_launch(void* const* d_in, const int* in_sizes, int n_in,
                              void* d_out, int out_size, void* d_ws, size_t ws_size,
                              hipStream_t stream)
{
  const float* xs      = (const float*)d_in[0];
  const int*   lengths = (const int*)d_in[1];
  const float* w_ih_f  = (const float*)d_in[3];
  const float* w_hh_f  = (const float*)d_in[4];
  const float* b_f     = (const float*)d_in[5];
  const float* w_ih_b  = (const float*)d_in[6];
  const float* w_hh_b  = (const float*)d_in[7];
  const float* b_b     = (const float*)d_in[8];
  const float* w_cls   = (const float*)d_in[9];
  const float* b_cls   = (const float*)d_in[10];
  float* out = (float*)d_out;

  auto alignup = [](size_t v) { return (v + 255) & ~(size_t)255; };
  const size_t hbuf_b  = alignup((size_t)2 * 2 * 32 * 32 * 16 * 2);       // 128 KB
  const size_t cbuf_b  = alignup((size_t)2 * B_N * H_N * 4);              // 128 KB
  const size_t flag_b  = alignup((size_t)64 * 64 * 4);                    // 16 KB
  const size_t lpart_b = alignup((size_t)64 * B_N * T_N * 2 * 4);         // 16 MB
  const size_t fixed = hbuf_b + cbuf_b + flag_b + lpart_b + 1024;

  int nseg = 1;
  while (nseg < 64) {
    const size_t xwb = alignup((size_t)2 * (T_N / nseg) * G4_N * B_N * 2);
    if (xwb + fixed <= ws_size) break;
    nseg <<= 1;
  }
  const int Tseg = T_N / nseg;
  const size_t xw_b = alignup((size_t)2 * Tseg * G4_N * B_N * 2);

  char* p = (char*)d_ws;
  unsigned short* xw = (unsigned short*)p;      p += xw_b;
  unsigned short* h_buf = (unsigned short*)p;   p += hbuf_b;
  float* c_buf = (float*)p;                     p += cbuf_b;
  unsigned int* flags = (unsigned int*)p;       p += flag_b;
  float* lpart = (float*)p;                     p += lpart_b;

  // zero h/c/flags (contiguous) and logits partials
  hipMemsetAsync(h_buf, 0, hbuf_b + cbuf_b + flag_b, stream);
  hipMemsetAsync(lpart, 0, lpart_b, stream);

  for (int s = 0; s < nseg; ++s) {
    const int t0 = s * Tseg;
    dim3 g(G4_N / 64, (Tseg * B_N) / 64, 2);
    xw_gemm_kernel<<<g, 256, 0, stream>>>(xs, lengths, w_ih_f, b_f, w_ih_b, b_b, xw, t0, Tseg);
    rec_kernel<<<64, 256, 0, stream>>>(xw, w_hh_f, w_hh_b, w_cls, lengths,
                                       h_buf, c_buf, lpart, flags + s * 64, t0, Tseg);
  }

  reduce_softmax_kernel<<<128, 256, 0, stream>>>(lpart, b_cls, out);
}

// Round 3
// 7284.986 us; speedup vs baseline: 2.4216x; 1.0960x over previous
//
#include <hip/hip_runtime.h>
#include <math.h>

#define B_N 32
#define T_N 1024
#define E_N 512
#define H_N 512
#define G4_N 2048  // 4*H

typedef __attribute__((ext_vector_type(8))) short short8;
typedef __attribute__((ext_vector_type(4))) float f32x4;

__device__ __forceinline__ unsigned short f2bfu(float f) {
  unsigned int x = __builtin_bit_cast(unsigned int, f);
  x += 0x7fffu + ((x >> 16) & 1u);
  return (unsigned short)(x >> 16);
}
__device__ __forceinline__ float bfu2f(unsigned short u) {
  return __builtin_bit_cast(float, ((unsigned int)u) << 16);
}
__device__ __forceinline__ float sigmf(float x) { return 1.0f / (1.0f + expf(-x)); }

// ---------------------------------------------------------------------------
// Kernel 1 (unchanged): xw[dir][t_local][g][b] bf16 = W_ih[dir] @ x(+rev) + b
// ---------------------------------------------------------------------------
__global__ __launch_bounds__(256) void xw_gemm_kernel(
    const float* __restrict__ xs, const int* __restrict__ lengths,
    const float* __restrict__ w_ih_f, const float* __restrict__ b_f,
    const float* __restrict__ w_ih_b, const float* __restrict__ b_b,
    unsigned short* __restrict__ xw, int t0, int Tseg)
{
  __shared__ unsigned short As[64][80];
  __shared__ unsigned short Bs[64][80];
  const int g0 = blockIdx.x * 64;
  const int n0 = blockIdx.y * 64;
  const int dir = blockIdx.z;
  const float* __restrict__ W = dir ? w_ih_b : w_ih_f;
  const float* __restrict__ bias = dir ? b_b : b_f;
  const int tid = threadIdx.x;
  const int w = tid >> 6, lane = tid & 63;
  const int wr = w >> 1, wc = w & 1;

  const int sr = tid >> 2;
  const int sq = tid & 3;
  const int nrow = n0 + sr;
  const int bb = nrow & 31;
  const int tt = t0 + (nrow >> 5);
  const int Lb = lengths[bb];
  const int src_t = (dir != 0 && tt < Lb) ? (Lb - 1 - tt) : tt;
  const float* __restrict__ xrow = xs + ((size_t)bb * T_N + src_t) * E_N;
  const float* __restrict__ arow = W + (size_t)(g0 + sr) * E_N;

  f32x4 acc[2][2] = {};

  for (int k0 = 0; k0 < E_N; k0 += 64) {
    float4 av[4], bv[4];
#pragma unroll
    for (int i = 0; i < 4; ++i) {
      av[i] = *(const float4*)&arow[k0 + sq * 16 + i * 4];
      bv[i] = *(const float4*)&xrow[k0 + sq * 16 + i * 4];
    }
    __syncthreads();
#pragma unroll
    for (int i = 0; i < 4; ++i) {
      ushort4 a4, b4;
      a4.x = f2bfu(av[i].x); a4.y = f2bfu(av[i].y); a4.z = f2bfu(av[i].z); a4.w = f2bfu(av[i].w);
      b4.x = f2bfu(bv[i].x); b4.y = f2bfu(bv[i].y); b4.z = f2bfu(bv[i].z); b4.w = f2bfu(bv[i].w);
      *(ushort4*)&As[sr][sq * 16 + i * 4] = a4;
      *(ushort4*)&Bs[sr][sq * 16 + i * 4] = b4;
    }
    __syncthreads();
#pragma unroll
    for (int kk = 0; kk < 2; ++kk) {
      const int ko = kk * 32 + ((lane >> 4) << 3);
      short8 bf0 = *(const short8*)&Bs[wc * 32 + (lane & 15)][ko];
      short8 bf1 = *(const short8*)&Bs[wc * 32 + 16 + (lane & 15)][ko];
      short8 af0 = *(const short8*)&As[wr * 32 + (lane & 15)][ko];
      short8 af1 = *(const short8*)&As[wr * 32 + 16 + (lane & 15)][ko];
      acc[0][0] = __builtin_amdgcn_mfma_f32_16x16x32_bf16(af0, bf0, acc[0][0], 0, 0, 0);
      acc[0][1] = __builtin_amdgcn_mfma_f32_16x16x32_bf16(af0, bf1, acc[0][1], 0, 0, 0);
      acc[1][0] = __builtin_amdgcn_mfma_f32_16x16x32_bf16(af1, bf0, acc[1][0], 0, 0, 0);
      acc[1][1] = __builtin_amdgcn_mfma_f32_16x16x32_bf16(af1, bf1, acc[1][1], 0, 0, 0);
    }
  }

#pragma unroll
  for (int mt = 0; mt < 2; ++mt)
#pragma unroll
    for (int nt = 0; nt < 2; ++nt)
#pragma unroll
      for (int j = 0; j < 4; ++j) {
        const int m = g0 + wr * 32 + mt * 16 + ((lane >> 4) << 2) + j;
        const int n = n0 + wc * 32 + nt * 16 + (lane & 15);
        const int tl = n >> 5, b = n & 31;
        const float v = acc[mt][nt][j] + bias[m];
        xw[(((size_t)dir * Tseg + tl) * G4_N + m) * B_N + b] = f2bfu(v);
      }
}

// ---------------------------------------------------------------------------
// Kernel 2: persistent recurrence with single-hop tagged-message exchange.
// msgs: [dir][parity][p=32][b=32][c2=8] x 8B, msg = {hi32: tag, lo32: 2xbf16}.
// Tag t = "h state entering step t". Producer (wg dir,cg) thread (b,c2) owns
// cols colbase+2c2,+1 of batch b. All-to-all dependency bounds skew < 2 steps
// so parity slots + exact-tag polling are race-free (no fences, no vmcnt).
// ---------------------------------------------------------------------------
__global__ __launch_bounds__(256, 1) void rec_kernel(
    const unsigned short* __restrict__ xw,
    const float* __restrict__ w_hh_f, const float* __restrict__ w_hh_b,
    const float* __restrict__ w_cls, const int* __restrict__ lengths,
    unsigned long long* __restrict__ msgs,   // [2][2][32][32][8] x 8B
    float* __restrict__ c_buf,               // [2][B][H]
    float* __restrict__ lpart,               // [64 wg][B][T][2]
    int t0, int Tseg)
{
  __shared__ unsigned short Ah[32][520];   // 33.3 KB, row stride 1040B
  __shared__ float gate_s[4][32][17];      // padded: conflict-light
  __shared__ float lp[8][34][2];

  const int tid = threadIdx.x;
  const int wg = blockIdx.x;
  const int dir = wg & 1;
  const int cg = wg >> 1;
  const int colbase = cg * 16;
  const float* __restrict__ w_hh = dir ? w_hh_b : w_hh_f;
  const int w = tid >> 6, lane = tid & 63;

  // --- one-time: W_hh B-fragments straight into registers (global f32 -> bf16)
  short8 wfrag[16];
  {
    const int grow = w * 512 + colbase + (lane & 15);
    const int kb = (lane >> 4) << 3;
    const float* __restrict__ wr = &w_hh[(size_t)grow * H_N];
#pragma unroll
    for (int ks = 0; ks < 16; ++ks) {
      const float4 f0 = *(const float4*)&wr[ks * 32 + kb];
      const float4 f1 = *(const float4*)&wr[ks * 32 + kb + 4];
      short8 v;
      v[0] = (short)f2bfu(f0.x); v[1] = (short)f2bfu(f0.y);
      v[2] = (short)f2bfu(f0.z); v[3] = (short)f2bfu(f0.w);
      v[4] = (short)f2bfu(f1.x); v[5] = (short)f2bfu(f1.y);
      v[6] = (short)f2bfu(f1.z); v[7] = (short)f2bfu(f1.w);
      wfrag[ks] = v;
    }
  }

  // --- per-thread epilogue ownership: b = tid>>3 (32), c2 = tid&7 (8)
  const int b = tid >> 3;
  const int c2 = tid & 7;
  const int col0 = colbase + c2 * 2, col1 = col0 + 1;
  const int Lb = lengths[b];
  const int Lb_r = lengths[tid & 31];      // for the tid<32 logits reducer
  float cc0 = c_buf[((size_t)dir * B_N + b) * H_N + col0];
  float cc1 = c_buf[((size_t)dir * B_N + b) * H_N + col1];
  const float wc00 = w_cls[0 * (2 * H_N) + dir * H_N + col0];
  const float wc01 = w_cls[0 * (2 * H_N) + dir * H_N + col1];
  const float wc10 = w_cls[1 * (2 * H_N) + dir * H_N + col0];
  const float wc11 = w_cls[1 * (2 * H_N) + dir * H_N + col1];

  // initial h from our own message slot (previous dispatch / init published it)
  float hh0, hh1;
  {
    const unsigned long long own =
        msgs[((size_t)dir * 2 + (t0 & 1)) * 8192 + ((size_t)cg * 32 + b) * 8 + c2];
    hh0 = bfu2f((unsigned short)(own & 0xffffu));
    hh1 = bfu2f((unsigned short)((own >> 16) & 0xffffu));
  }

  float* __restrict__ lslice = lpart + (size_t)wg * B_N * T_N * 2;

  // pre-issue step-0 message loads
  unsigned long long m[32];
  {
    const unsigned long long* __restrict__ mb = msgs + ((size_t)dir * 2 + (t0 & 1)) * 8192;
#pragma unroll
    for (int j = 0; j < 32; ++j)
      m[j] = __hip_atomic_load(&mb[j * 256 + tid], __ATOMIC_RELAXED, __HIP_MEMORY_SCOPE_AGENT);
  }

  for (int ts = 0; ts < Tseg; ++ts) {
    const int t = t0 + ts;

    // prefetch this step's xw gate values (8 scalars; consumed in epilogue)
    unsigned short xv[8];
    {
      const unsigned short* __restrict__ xbase =
          &xw[((size_t)(dir * Tseg + ts) * G4_N + colbase + c2 * 2) * B_N + b];
#pragma unroll
      for (int q = 0; q < 4; ++q) {
        xv[q * 2]     = xbase[q * 16384];
        xv[q * 2 + 1] = xbase[q * 16384 + 32];
      }
    }

    // poll tagged messages; accepted payloads go straight to Ah
    {
      const unsigned long long* __restrict__ mb = msgs + ((size_t)dir * 2 + (t & 1)) * 8192;
      const unsigned int want = (unsigned int)t;
      unsigned int pend = 0xffffffffu;
      while (pend) {
        unsigned int np = 0;
#pragma unroll
        for (int j = 0; j < 32; ++j) {
          if (pend & (1u << j)) {
            if ((unsigned int)(m[j] >> 32) == want)
              *(unsigned int*)&Ah[b][j * 16 + c2 * 2] = (unsigned int)(m[j] & 0xffffffffu);
            else
              np |= 1u << j;
          }
        }
        if (np) {
#pragma unroll
          for (int j = 0; j < 32; ++j)
            if (np & (1u << j))
              m[j] = __hip_atomic_load(&mb[j * 256 + tid], __ATOMIC_RELAXED, __HIP_MEMORY_SCOPE_AGENT);
        }
        pend = np;
      }
    }
    __syncthreads();  // SYNC1: Ah ready

    // previous step's logits reduce (off critical path; lp stable until next epilogue)
    if (ts > 0 && tid < 32) {
      const int tp = t - 1;
      if (tp < Lb_r) {
        float s0 = 0.f, s1 = 0.f;
#pragma unroll
        for (int k = 0; k < 8; ++k) { s0 += lp[k][tid][0]; s1 += lp[k][tid][1]; }
        const int tpos = dir ? (Lb_r - 1 - tp) : tp;
        float2 v; v.x = s0; v.y = s1;
        *(float2*)&lslice[((size_t)tid * T_N + tpos) * 2] = v;
      }
    }

    // MFMA: D[b][gate-row] ; wave w = gate q
    {
      f32x4 acc0 = {0.f, 0.f, 0.f, 0.f}, acc1 = {0.f, 0.f, 0.f, 0.f};
      const int kb = (lane >> 4) << 3;
#pragma unroll
      for (int ks = 0; ks < 16; ++ks) {
        const int kk = (ks << 5) + kb;
        short8 a0 = *(const short8*)&Ah[(lane & 15)][kk];
        short8 a1 = *(const short8*)&Ah[16 + (lane & 15)][kk];
        acc0 = __builtin_amdgcn_mfma_f32_16x16x32_bf16(a0, wfrag[ks], acc0, 0, 0, 0);
        acc1 = __builtin_amdgcn_mfma_f32_16x16x32_bf16(a1, wfrag[ks], acc1, 0, 0, 0);
      }
      const int crow = (lane >> 4) << 2;
      const int ccol = lane & 15;
#pragma unroll
      for (int j = 0; j < 4; ++j) {
        gate_s[w][crow + j][ccol] = acc0[j];
        gate_s[w][16 + crow + j][ccol] = acc1[j];
      }
    }
    __syncthreads();  // SYNC2: gate_s ready

    // epilogue: gates + state update (fp32)
    const bool valid = (t < Lb);
    float hn0, hn1;
    {
      const int cl0 = c2 * 2, cl1 = cl0 + 1;
      float gi = gate_s[0][b][cl0] + bfu2f(xv[0]);
      float gf = gate_s[1][b][cl0] + bfu2f(xv[2]);
      float gg = gate_s[2][b][cl0] + bfu2f(xv[4]);
      float go = gate_s[3][b][cl0] + bfu2f(xv[6]);
      float cn = sigmf(gf) * cc0 + sigmf(gi) * tanhf(gg);
      hn0 = sigmf(go) * tanhf(cn);
      if (valid) { cc0 = cn; hh0 = hn0; }

      gi = gate_s[0][b][cl1] + bfu2f(xv[1]);
      gf = gate_s[1][b][cl1] + bfu2f(xv[3]);
      gg = gate_s[2][b][cl1] + bfu2f(xv[5]);
      go = gate_s[3][b][cl1] + bfu2f(xv[7]);
      cn = sigmf(gf) * cc1 + sigmf(gi) * tanhf(gg);
      hn1 = sigmf(go) * tanhf(cn);
      if (valid) { cc1 = cn; hh1 = hn1; }
    }

    // publish tagged message (fire-and-forget, coalesced)
    {
      const unsigned long long out =
          ((unsigned long long)(unsigned int)(t + 1) << 32) |
          (unsigned long long)((unsigned int)f2bfu(hh0) | ((unsigned int)f2bfu(hh1) << 16));
      __hip_atomic_store(&msgs[((size_t)dir * 2 + ((t + 1) & 1)) * 8192 + ((size_t)cg * 32 + b) * 8 + c2],
                         out, __ATOMIC_RELAXED, __HIP_MEMORY_SCOPE_AGENT);
    }
    lp[c2][b][0] = valid ? (hn0 * wc00 + hn1 * wc01) : 0.f;
    lp[c2][b][1] = valid ? (hn0 * wc10 + hn1 * wc11) : 0.f;

    // pre-issue next step's message loads; the barrier's vmcnt drain overlaps
    {
      const unsigned long long* __restrict__ mb = msgs + ((size_t)dir * 2 + ((t + 1) & 1)) * 8192;
#pragma unroll
      for (int j = 0; j < 32; ++j)
        m[j] = __hip_atomic_load(&mb[j * 256 + tid], __ATOMIC_RELAXED, __HIP_MEMORY_SCOPE_AGENT);
    }
    __syncthreads();  // SYNC2b: lp complete, gate_s/Ah reusable
  }

  // final step's logits reduce
  if (tid < 32) {
    const int tp = t0 + Tseg - 1;
    if (tp < Lb_r) {
      float s0 = 0.f, s1 = 0.f;
#pragma unroll
      for (int k = 0; k < 8; ++k) { s0 += lp[k][tid][0]; s1 += lp[k][tid][1]; }
      const int tpos = dir ? (Lb_r - 1 - tp) : tp;
      float2 v; v.x = s0; v.y = s1;
      *(float2*)&lslice[((size_t)tid * T_N + tpos) * 2] = v;
    }
  }

  // persist c across segment launches (h persists via msgs)
  c_buf[((size_t)dir * B_N + b) * H_N + col0] = cc0;
  c_buf[((size_t)dir * B_N + b) * H_N + col1] = cc1;
}

// ---------------------------------------------------------------------------
__global__ void init_kernel(unsigned long long* __restrict__ msgs,
                            float* __restrict__ c_buf)
{
  const int i = blockIdx.x * 256 + threadIdx.x;  // 0..65535
  if (i < 2 * 2 * 32 * 32 * 8) msgs[i] = 0ull;   // tag 0, h = 0
  if (i < 2 * B_N * H_N) c_buf[i] = 0.f;
}

__global__ void reduce_softmax_kernel(const float* __restrict__ lpart,
                                      const float* __restrict__ b_cls,
                                      float* __restrict__ out)
{
  const int i = blockIdx.x * 256 + threadIdx.x;  // 0..32767
  if (i >= B_N * T_N) return;
  float s0 = b_cls[0], s1 = b_cls[1];
  const float* __restrict__ p = lpart + (size_t)i * 2;
#pragma unroll 8
  for (int wg = 0; wg < 64; ++wg) {
    s0 += p[(size_t)wg * B_N * T_N * 2];
    s1 += p[(size_t)wg * B_N * T_N * 2 + 1];
  }
  const float m = fmaxf(s0, s1);
  const float e0 = expf(s0 - m), e1 = expf(s1 - m);
  const float inv = 1.f / (e0 + e1);
  out[2 * i] = e0 * inv;
  out[2 * i + 1] = e1 * inv;
}

// ---------------------------------------------------------------------------
extern "C" void kernel_launch(void* const* d_in, const int* in_sizes, int n_in,
                              void* d_out, int out_size, void* d_ws, size_t ws_size,
                              hipStream_t stream)
{
  const float* xs      = (const float*)d_in[0];
  const int*   lengths = (const int*)d_in[1];
  const float* w_ih_f  = (const float*)d_in[3];
  const float* w_hh_f  = (const float*)d_in[4];
  const float* b_f     = (const float*)d_in[5];
  const float* w_ih_b  = (const float*)d_in[6];
  const float* w_hh_b  = (const float*)d_in[7];
  const float* b_b     = (const float*)d_in[8];
  const float* w_cls   = (const float*)d_in[9];
  const float* b_cls   = (const float*)d_in[10];
  float* out = (float*)d_out;

  auto alignup = [](size_t v) { return (v + 255) & ~(size_t)255; };
  const size_t msgs_b  = alignup((size_t)2 * 2 * 32 * 32 * 8 * 8);        // 256 KB
  const size_t cbuf_b  = alignup((size_t)2 * B_N * H_N * 4);              // 128 KB
  const size_t lpart_b = alignup((size_t)64 * B_N * T_N * 2 * 4);         // 16 MB
  const size_t fixed = msgs_b + cbuf_b + lpart_b + 1024;

  int nseg = 1;
  while (nseg < 64) {
    const size_t xwb = alignup((size_t)2 * (T_N / nseg) * G4_N * B_N * 2);
    if (xwb + fixed <= ws_size) break;
    nseg <<= 1;
  }
  const int Tseg = T_N / nseg;
  const size_t xw_b = alignup((size_t)2 * Tseg * G4_N * B_N * 2);

  char* p = (char*)d_ws;
  unsigned short* xw = (unsigned short*)p;        p += xw_b;
  unsigned long long* msgs = (unsigned long long*)p; p += msgs_b;
  float* c_buf = (float*)p;                       p += cbuf_b;
  float* lpart = (float*)p;                       p += lpart_b;

  hipMemsetAsync(lpart, 0, lpart_b, stream);
  init_kernel<<<256, 256, 0, stream>>>(msgs, c_buf);

  for (int s = 0; s < nseg; ++s) {
    const int t0 = s * Tseg;
    dim3 g(G4_N / 64, (Tseg * B_N) / 64, 2);
    xw_gemm_kernel<<<g, 256, 0, stream>>>(xs, lengths, w_ih_f, b_f, w_ih_b, b_b, xw, t0, Tseg);
    rec_kernel<<<64, 256, 0, stream>>>(xw, w_hh_f, w_hh_b, w_cls, lengths,
                                       msgs, c_buf, lpart, t0, Tseg);
  }

  reduce_softmax_kernel<<<128, 256, 0, stream>>>(lpart, b_cls, out);
}

// Round 4
// 5768.078 us; speedup vs baseline: 3.0584x; 1.2630x over previous
//
#include <hip/hip_runtime.h>
#include <math.h>

#define B_N 32
#define T_N 1024
#define E_N 512
#define H_N 512
#define G4_N 2048  // 4*H

typedef __attribute__((ext_vector_type(8))) short short8;
typedef __attribute__((ext_vector_type(4))) float f32x4;
typedef unsigned long long ull;

__device__ __forceinline__ unsigned short f2bfu(float f) {
  unsigned int x = __builtin_bit_cast(unsigned int, f);
  x += 0x7fffu + ((x >> 16) & 1u);
  return (unsigned short)(x >> 16);
}
__device__ __forceinline__ float bfu2f(unsigned short u) {
  return __builtin_bit_cast(float, ((unsigned int)u) << 16);
}
__device__ __forceinline__ float sigmf(float x) { return 1.0f / (1.0f + expf(-x)); }

// ---------------------------------------------------------------------------
// Kernel 1 (unchanged): xw[dir][t_local][g][b] bf16 = W_ih[dir] @ x(+rev) + b
// ---------------------------------------------------------------------------
__global__ __launch_bounds__(256) void xw_gemm_kernel(
    const float* __restrict__ xs, const int* __restrict__ lengths,
    const float* __restrict__ w_ih_f, const float* __restrict__ b_f,
    const float* __restrict__ w_ih_b, const float* __restrict__ b_b,
    unsigned short* __restrict__ xw, int t0, int Tseg)
{
  __shared__ unsigned short As[64][80];
  __shared__ unsigned short Bs[64][80];
  const int g0 = blockIdx.x * 64;
  const int n0 = blockIdx.y * 64;
  const int dir = blockIdx.z;
  const float* __restrict__ W = dir ? w_ih_b : w_ih_f;
  const float* __restrict__ bias = dir ? b_b : b_f;
  const int tid = threadIdx.x;
  const int w = tid >> 6, lane = tid & 63;
  const int wr = w >> 1, wc = w & 1;

  const int sr = tid >> 2;
  const int sq = tid & 3;
  const int nrow = n0 + sr;
  const int bb = nrow & 31;
  const int tt = t0 + (nrow >> 5);
  const int Lb = lengths[bb];
  const int src_t = (dir != 0 && tt < Lb) ? (Lb - 1 - tt) : tt;
  const float* __restrict__ xrow = xs + ((size_t)bb * T_N + src_t) * E_N;
  const float* __restrict__ arow = W + (size_t)(g0 + sr) * E_N;

  f32x4 acc[2][2] = {};

  for (int k0 = 0; k0 < E_N; k0 += 64) {
    float4 av[4], bv[4];
#pragma unroll
    for (int i = 0; i < 4; ++i) {
      av[i] = *(const float4*)&arow[k0 + sq * 16 + i * 4];
      bv[i] = *(const float4*)&xrow[k0 + sq * 16 + i * 4];
    }
    __syncthreads();
#pragma unroll
    for (int i = 0; i < 4; ++i) {
      ushort4 a4, b4;
      a4.x = f2bfu(av[i].x); a4.y = f2bfu(av[i].y); a4.z = f2bfu(av[i].z); a4.w = f2bfu(av[i].w);
      b4.x = f2bfu(bv[i].x); b4.y = f2bfu(bv[i].y); b4.z = f2bfu(bv[i].z); b4.w = f2bfu(bv[i].w);
      *(ushort4*)&As[sr][sq * 16 + i * 4] = a4;
      *(ushort4*)&Bs[sr][sq * 16 + i * 4] = b4;
    }
    __syncthreads();
#pragma unroll
    for (int kk = 0; kk < 2; ++kk) {
      const int ko = kk * 32 + ((lane >> 4) << 3);
      short8 bf0 = *(const short8*)&Bs[wc * 32 + (lane & 15)][ko];
      short8 bf1 = *(const short8*)&Bs[wc * 32 + 16 + (lane & 15)][ko];
      short8 af0 = *(const short8*)&As[wr * 32 + (lane & 15)][ko];
      short8 af1 = *(const short8*)&As[wr * 32 + 16 + (lane & 15)][ko];
      acc[0][0] = __builtin_amdgcn_mfma_f32_16x16x32_bf16(af0, bf0, acc[0][0], 0, 0, 0);
      acc[0][1] = __builtin_amdgcn_mfma_f32_16x16x32_bf16(af0, bf1, acc[0][1], 0, 0, 0);
      acc[1][0] = __builtin_amdgcn_mfma_f32_16x16x32_bf16(af1, bf0, acc[1][0], 0, 0, 0);
      acc[1][1] = __builtin_amdgcn_mfma_f32_16x16x32_bf16(af1, bf1, acc[1][1], 0, 0, 0);
    }
  }

#pragma unroll
  for (int mt = 0; mt < 2; ++mt)
#pragma unroll
    for (int nt = 0; nt < 2; ++nt)
#pragma unroll
      for (int j = 0; j < 4; ++j) {
        const int m = g0 + wr * 32 + mt * 16 + ((lane >> 4) << 2) + j;
        const int n = n0 + wc * 32 + nt * 16 + (lane & 15);
        const int tl = n >> 5, b = n & 31;
        const float v = acc[mt][nt][j] + bias[m];
        xw[(((size_t)dir * Tseg + tl) * G4_N + m) * B_N + b] = f2bfu(v);
      }
}

// ---------------------------------------------------------------------------
// Kernel 2: persistent recurrence, 512 threads/wg, single-hop tagged messages.
// msgs: [dir][parity][cg=32][b=32][c2=8] x 8B; msg = {hi32: tag, lo32: 2xbf16}.
// 8 waves: wave w -> gate q=w>>1, K-half kh=w&1; partials merged in LDS.
// Per-thread: 16 msg polls, 1 output column. Exactly 2 barriers per step.
// ---------------------------------------------------------------------------
__global__ __launch_bounds__(512, 1) void rec_kernel(
    const unsigned short* __restrict__ xw,
    const float* __restrict__ w_hh_f, const float* __restrict__ w_hh_b,
    const float* __restrict__ w_cls, const int* __restrict__ lengths,
    ull* __restrict__ msgs,                  // [2][2][32][32][8] x 8B
    float* __restrict__ c_buf,               // [2][B][H]
    float* __restrict__ lpart,               // [64 wg][B][T][2]
    int t0, int Tseg)
{
  __shared__ unsigned short Ah[32][520];   // 33.3 KB, row stride 1040B
  __shared__ float gate_p[8][32][17];      // K-half partials, 17.4 KB
  __shared__ float lp[16][33][2];          // logits partials, 4.2 KB

  const int tid = threadIdx.x;
  const int wg = blockIdx.x;
  const int dir = wg & 1;
  const int cg = wg >> 1;
  const int colbase = cg * 16;
  const float* __restrict__ w_hh = dir ? w_hh_b : w_hh_f;
  const int w = tid >> 6, lane = tid & 63;
  const int q = w >> 1, kh = w & 1;

  // --- one-time: W_hh fragments (this wave's gate q, K-half kh) into registers
  short8 wfrag[8];
  {
    const int grow = q * 512 + colbase + (lane & 15);
    const int kb = (lane >> 4) << 3;
    const float* __restrict__ wr_ = &w_hh[(size_t)grow * H_N + kh * 256];
#pragma unroll
    for (int ks = 0; ks < 8; ++ks) {
      const float4 f0 = *(const float4*)&wr_[ks * 32 + kb];
      const float4 f1 = *(const float4*)&wr_[ks * 32 + kb + 4];
      short8 v;
      v[0] = (short)f2bfu(f0.x); v[1] = (short)f2bfu(f0.y);
      v[2] = (short)f2bfu(f0.z); v[3] = (short)f2bfu(f0.w);
      v[4] = (short)f2bfu(f1.x); v[5] = (short)f2bfu(f1.y);
      v[6] = (short)f2bfu(f1.z); v[7] = (short)f2bfu(f1.w);
      wfrag[ks] = v;
    }
  }

  // --- per-thread epilogue ownership: b = tid>>4 (32), cl = tid&15 (16 cols)
  const int b = tid >> 4;
  const int cl = tid & 15;
  const int col = colbase + cl;
  const int Lb = lengths[b];
  const int Lb_r = lengths[tid & 31];      // for the tid<64 logits reducer
  float cc = c_buf[((size_t)dir * B_N + b) * H_N + col];
  const float wc0 = w_cls[dir * H_N + col];
  const float wc1 = w_cls[2 * H_N + dir * H_N + col];

  // initial h from our own message slot
  float hh;
  {
    const ull own = msgs[((size_t)dir * 2 + (t0 & 1)) * 8192 + (size_t)cg * 256 + b * 8 + (cl >> 1)];
    hh = bfu2f((unsigned short)((own >> ((cl & 1) * 16)) & 0xffffu));
  }

  float* __restrict__ lslice = lpart + (size_t)wg * B_N * T_N * 2;

  // pre-issue step-0 message loads (16 per thread)
  ull m[16];
  {
    const ull* __restrict__ mb = msgs + ((size_t)dir * 2 + (t0 & 1)) * 8192;
#pragma unroll
    for (int j = 0; j < 16; ++j)
      m[j] = __hip_atomic_load(&mb[j * 512 + tid], __ATOMIC_RELAXED, __HIP_MEMORY_SCOPE_AGENT);
  }

  for (int ts = 0; ts < Tseg; ++ts) {
    const int t = t0 + ts;

    // prefetch this step's xw gate values (4 scalars, consumed in epilogue)
    unsigned short xv[4];
    {
      const unsigned short* __restrict__ xb =
          &xw[((size_t)(dir * Tseg + ts) * G4_N + colbase + cl) * B_N + b];
#pragma unroll
      for (int q2 = 0; q2 < 4; ++q2) xv[q2] = xb[(size_t)q2 * 512 * B_N];
    }

    // poll tagged messages; accepted payloads go straight to Ah
    {
      const ull* __restrict__ mb = msgs + ((size_t)dir * 2 + (t & 1)) * 8192;
      const unsigned int want = (unsigned int)t;
      unsigned int pend = 0xffffu;
      while (pend) {
        unsigned int np = 0;
#pragma unroll
        for (int j = 0; j < 16; ++j) {
          if (pend & (1u << j)) {
            if ((unsigned int)(m[j] >> 32) == want) {
              const int i = j * 512 + tid;
              const int p = i >> 8, bb = (i >> 3) & 31, c2 = i & 7;
              *(unsigned int*)&Ah[bb][p * 16 + c2 * 2] = (unsigned int)(m[j] & 0xffffffffu);
            } else np |= 1u << j;
          }
        }
        if (np) {
#pragma unroll
          for (int j = 0; j < 16; ++j)
            if (np & (1u << j))
              m[j] = __hip_atomic_load(&mb[j * 512 + tid], __ATOMIC_RELAXED, __HIP_MEMORY_SCOPE_AGENT);
        }
        pend = np;
      }
    }
    __syncthreads();  // SYNC1: Ah complete (also: all threads done with prev lp)

    // previous step's logits reduce (off critical path; safe after SYNC1)
    if (ts > 0 && tid < 64) {
      const int br = tid & 31, tau = tid >> 5;
      const int tp = t - 1;
      if (tp < Lb_r) {
        float s = 0.f;
#pragma unroll
        for (int k = 0; k < 16; ++k) s += lp[k][br][tau];
        const int tpos = dir ? (Lb_r - 1 - tp) : tp;
        lslice[((size_t)br * T_N + tpos) * 2 + tau] = s;
      }
    }

    // MFMA: wave w computes gate q, K-half kh partials
    {
      f32x4 acc0 = {0.f, 0.f, 0.f, 0.f}, acc1 = {0.f, 0.f, 0.f, 0.f};
      const int kb = (lane >> 4) << 3;
#pragma unroll
      for (int ks = 0; ks < 8; ++ks) {
        const int kk = kh * 256 + (ks << 5) + kb;
        short8 a0 = *(const short8*)&Ah[(lane & 15)][kk];
        short8 a1 = *(const short8*)&Ah[16 + (lane & 15)][kk];
        acc0 = __builtin_amdgcn_mfma_f32_16x16x32_bf16(a0, wfrag[ks], acc0, 0, 0, 0);
        acc1 = __builtin_amdgcn_mfma_f32_16x16x32_bf16(a1, wfrag[ks], acc1, 0, 0, 0);
      }
      const int crow = (lane >> 4) << 2;
      const int ccol = lane & 15;
#pragma unroll
      for (int j = 0; j < 4; ++j) {
        gate_p[w][crow + j][ccol] = acc0[j];
        gate_p[w][16 + crow + j][ccol] = acc1[j];
      }
    }
    __syncthreads();  // SYNC2: gate_p ready

    // epilogue: merge K-halves, gates + state update (fp32)
    const bool valid = (t < Lb);
    float hn;
    {
      const float gi = gate_p[0][b][cl] + gate_p[1][b][cl] + bfu2f(xv[0]);
      const float gf = gate_p[2][b][cl] + gate_p[3][b][cl] + bfu2f(xv[1]);
      const float gg = gate_p[4][b][cl] + gate_p[5][b][cl] + bfu2f(xv[2]);
      const float go = gate_p[6][b][cl] + gate_p[7][b][cl] + bfu2f(xv[3]);
      const float cn = sigmf(gf) * cc + sigmf(gi) * tanhf(gg);
      hn = sigmf(go) * tanhf(cn);
      if (valid) { cc = cn; hh = hn; }
    }

    // publish tagged message: adjacent-column pair via shfl (lane&1 == cl&1)
    {
      const float hhp = __shfl_xor(hh, 1);
      if ((cl & 1) == 0) {
        const unsigned int payload = (unsigned int)f2bfu(hh) | ((unsigned int)f2bfu(hhp) << 16);
        const ull out = ((ull)(unsigned int)(t + 1) << 32) | (ull)payload;
        __hip_atomic_store(&msgs[((size_t)dir * 2 + ((t + 1) & 1)) * 8192 + (size_t)cg * 256 + b * 8 + (cl >> 1)],
                           out, __ATOMIC_RELAXED, __HIP_MEMORY_SCOPE_AGENT);
      }
    }
    lp[cl][b][0] = valid ? hn * wc0 : 0.f;
    lp[cl][b][1] = valid ? hn * wc1 : 0.f;

    // pre-issue next step's message loads; in flight across the loop-back
    {
      const ull* __restrict__ mb = msgs + ((size_t)dir * 2 + ((t + 1) & 1)) * 8192;
#pragma unroll
      for (int j = 0; j < 16; ++j)
        m[j] = __hip_atomic_load(&mb[j * 512 + tid], __ATOMIC_RELAXED, __HIP_MEMORY_SCOPE_AGENT);
    }
    // no barrier here: next SYNC1 provides all needed ordering
  }

  // final step's logits reduce
  if (tid < 64) {
    const int br = tid & 31, tau = tid >> 5;
    const int tp = t0 + Tseg - 1;
    if (tp < Lb_r) {
      float s = 0.f;
#pragma unroll
      for (int k = 0; k < 16; ++k) s += lp[k][br][tau];
      const int tpos = dir ? (Lb_r - 1 - tp) : tp;
      lslice[((size_t)br * T_N + tpos) * 2 + tau] = s;
    }
  }

  // persist c across segment launches (h persists via msgs)
  c_buf[((size_t)dir * B_N + b) * H_N + col] = cc;
}

// ---------------------------------------------------------------------------
__global__ void init_kernel(ull* __restrict__ msgs, float* __restrict__ c_buf)
{
  const int i = blockIdx.x * 256 + threadIdx.x;  // 0..65535
  if (i < 2 * 2 * 32 * 32 * 8) msgs[i] = 0ull;   // tag 0, h = 0
  if (i < 2 * B_N * H_N) c_buf[i] = 0.f;
}

__global__ void reduce_softmax_kernel(const float* __restrict__ lpart,
                                      const float* __restrict__ b_cls,
                                      float* __restrict__ out)
{
  const int i = blockIdx.x * 256 + threadIdx.x;  // 0..32767
  if (i >= B_N * T_N) return;
  float s0 = b_cls[0], s1 = b_cls[1];
  const float* __restrict__ p = lpart + (size_t)i * 2;
#pragma unroll 8
  for (int wg = 0; wg < 64; ++wg) {
    s0 += p[(size_t)wg * B_N * T_N * 2];
    s1 += p[(size_t)wg * B_N * T_N * 2 + 1];
  }
  const float m = fmaxf(s0, s1);
  const float e0 = expf(s0 - m), e1 = expf(s1 - m);
  const float inv = 1.f / (e0 + e1);
  out[2 * i] = e0 * inv;
  out[2 * i + 1] = e1 * inv;
}

// ---------------------------------------------------------------------------
extern "C" void kernel_launch(void* const* d_in, const int* in_sizes, int n_in,
                              void* d_out, int out_size, void* d_ws, size_t ws_size,
                              hipStream_t stream)
{
  const float* xs      = (const float*)d_in[0];
  const int*   lengths = (const int*)d_in[1];
  const float* w_ih_f  = (const float*)d_in[3];
  const float* w_hh_f  = (const float*)d_in[4];
  const float* b_f     = (const float*)d_in[5];
  const float* w_ih_b  = (const float*)d_in[6];
  const float* w_hh_b  = (const float*)d_in[7];
  const float* b_b     = (const float*)d_in[8];
  const float* w_cls   = (const float*)d_in[9];
  const float* b_cls   = (const float*)d_in[10];
  float* out = (float*)d_out;

  auto alignup = [](size_t v) { return (v + 255) & ~(size_t)255; };
  const size_t msgs_b  = alignup((size_t)2 * 2 * 32 * 32 * 8 * 8);        // 256 KB
  const size_t cbuf_b  = alignup((size_t)2 * B_N * H_N * 4);              // 128 KB
  const size_t lpart_b = alignup((size_t)64 * B_N * T_N * 2 * 4);         // 16 MB
  const size_t fixed = msgs_b + cbuf_b + lpart_b + 1024;

  int nseg = 1;
  while (nseg < 64) {
    const size_t xwb = alignup((size_t)2 * (T_N / nseg) * G4_N * B_N * 2);
    if (xwb + fixed <= ws_size) break;
    nseg <<= 1;
  }
  const int Tseg = T_N / nseg;
  const size_t xw_b = alignup((size_t)2 * Tseg * G4_N * B_N * 2);

  char* p = (char*)d_ws;
  unsigned short* xw = (unsigned short*)p;  p += xw_b;
  ull* msgs = (ull*)p;                      p += msgs_b;
  float* c_buf = (float*)p;                 p += cbuf_b;
  float* lpart = (float*)p;                 p += lpart_b;

  hipMemsetAsync(lpart, 0, lpart_b, stream);
  init_kernel<<<256, 256, 0, stream>>>(msgs, c_buf);

  for (int s = 0; s < nseg; ++s) {
    const int t0 = s * Tseg;
    dim3 g(G4_N / 64, (Tseg * B_N) / 64, 2);
    xw_gemm_kernel<<<g, 256, 0, stream>>>(xs, lengths, w_ih_f, b_f, w_ih_b, b_b, xw, t0, Tseg);
    rec_kernel<<<64, 512, 0, stream>>>(xw, w_hh_f, w_hh_b, w_cls, lengths,
                                       msgs, c_buf, lpart, t0, Tseg);
  }

  reduce_softmax_kernel<<<128, 256, 0, stream>>>(lpart, b_cls, out);
}

// Round 6
// 4329.602 us; speedup vs baseline: 4.0745x; 1.3322x over previous
//
#include <hip/hip_runtime.h>
#include <math.h>

#define B_N 32
#define T_N 1024
#define E_N 512
#define H_N 512
#define G4_N 2048  // 4*H

typedef __attribute__((ext_vector_type(8))) short short8;
typedef __attribute__((ext_vector_type(4))) float f32x4;
typedef __attribute__((ext_vector_type(4))) unsigned int uint32x4;
typedef unsigned long long ull;

__device__ __forceinline__ unsigned short f2bfu(float f) {
  unsigned int x = __builtin_bit_cast(unsigned int, f);
  x += 0x7fffu + ((x >> 16) & 1u);
  return (unsigned short)(x >> 16);
}
__device__ __forceinline__ float bfu2f(unsigned short u) {
  return __builtin_bit_cast(float, ((unsigned int)u) << 16);
}
__device__ __forceinline__ float sigmf(float x) { return 1.0f / (1.0f + expf(-x)); }

// ---- agent-scope (MALL-coherent, L1+L2 bypass) access helpers -------------
__device__ __forceinline__ void load64_mall(const unsigned short* p,
                                            uint32x4& a, uint32x4& b,
                                            uint32x4& c, uint32x4& d) {
  asm volatile("global_load_dwordx4 %0, %4, off sc0 sc1\n\t"
               "global_load_dwordx4 %1, %4, off offset:16 sc0 sc1\n\t"
               "global_load_dwordx4 %2, %4, off offset:32 sc0 sc1\n\t"
               "global_load_dwordx4 %3, %4, off offset:48 sc0 sc1\n\t"
               "s_waitcnt vmcnt(0)"
               : "=&v"(a), "=&v"(b), "=&v"(c), "=&v"(d)
               : "v"(p) : "memory");
}
__device__ __forceinline__ void store32_mall(unsigned int* p, unsigned int v) {
  asm volatile("global_store_dword %0, %1, off sc0 sc1" :: "v"(p), "v"(v) : "memory");
}

// ---------------------------------------------------------------------------
// Kernel 1 (unchanged): xw[dir][t_local][g][b] bf16 = W_ih[dir] @ x(+rev) + b
// ---------------------------------------------------------------------------
__global__ __launch_bounds__(256) void xw_gemm_kernel(
    const float* __restrict__ xs, const int* __restrict__ lengths,
    const float* __restrict__ w_ih_f, const float* __restrict__ b_f,
    const float* __restrict__ w_ih_b, const float* __restrict__ b_b,
    unsigned short* __restrict__ xw, int t0, int Tseg)
{
  __shared__ unsigned short As[64][80];
  __shared__ unsigned short Bs[64][80];
  const int g0 = blockIdx.x * 64;
  const int n0 = blockIdx.y * 64;
  const int dir = blockIdx.z;
  const float* __restrict__ W = dir ? w_ih_b : w_ih_f;
  const float* __restrict__ bias = dir ? b_b : b_f;
  const int tid = threadIdx.x;
  const int w = tid >> 6, lane = tid & 63;
  const int wr = w >> 1, wc = w & 1;

  const int sr = tid >> 2;
  const int sq = tid & 3;
  const int nrow = n0 + sr;
  const int bb = nrow & 31;
  const int tt = t0 + (nrow >> 5);
  const int Lb = lengths[bb];
  const int src_t = (dir != 0 && tt < Lb) ? (Lb - 1 - tt) : tt;
  const float* __restrict__ xrow = xs + ((size_t)bb * T_N + src_t) * E_N;
  const float* __restrict__ arow = W + (size_t)(g0 + sr) * E_N;

  f32x4 acc[2][2] = {};

  for (int k0 = 0; k0 < E_N; k0 += 64) {
    float4 av[4], bv[4];
#pragma unroll
    for (int i = 0; i < 4; ++i) {
      av[i] = *(const float4*)&arow[k0 + sq * 16 + i * 4];
      bv[i] = *(const float4*)&xrow[k0 + sq * 16 + i * 4];
    }
    __syncthreads();
#pragma unroll
    for (int i = 0; i < 4; ++i) {
      ushort4 a4, b4;
      a4.x = f2bfu(av[i].x); a4.y = f2bfu(av[i].y); a4.z = f2bfu(av[i].z); a4.w = f2bfu(av[i].w);
      b4.x = f2bfu(bv[i].x); b4.y = f2bfu(bv[i].y); b4.z = f2bfu(bv[i].z); b4.w = f2bfu(bv[i].w);
      *(ushort4*)&As[sr][sq * 16 + i * 4] = a4;
      *(ushort4*)&Bs[sr][sq * 16 + i * 4] = b4;
    }
    __syncthreads();
#pragma unroll
    for (int kk = 0; kk < 2; ++kk) {
      const int ko = kk * 32 + ((lane >> 4) << 3);
      short8 bf0 = *(const short8*)&Bs[wc * 32 + (lane & 15)][ko];
      short8 bf1 = *(const short8*)&Bs[wc * 32 + 16 + (lane & 15)][ko];
      short8 af0 = *(const short8*)&As[wr * 32 + (lane & 15)][ko];
      short8 af1 = *(const short8*)&As[wr * 32 + 16 + (lane & 15)][ko];
      acc[0][0] = __builtin_amdgcn_mfma_f32_16x16x32_bf16(af0, bf0, acc[0][0], 0, 0, 0);
      acc[0][1] = __builtin_amdgcn_mfma_f32_16x16x32_bf16(af0, bf1, acc[0][1], 0, 0, 0);
      acc[1][0] = __builtin_amdgcn_mfma_f32_16x16x32_bf16(af1, bf0, acc[1][0], 0, 0, 0);
      acc[1][1] = __builtin_amdgcn_mfma_f32_16x16x32_bf16(af1, bf1, acc[1][1], 0, 0, 0);
    }
  }

#pragma unroll
  for (int mt = 0; mt < 2; ++mt)
#pragma unroll
    for (int nt = 0; nt < 2; ++nt)
#pragma unroll
      for (int j = 0; j < 4; ++j) {
        const int m = g0 + wr * 32 + mt * 16 + ((lane >> 4) << 2) + j;
        const int n = n0 + wc * 32 + nt * 16 + (lane & 15);
        const int tl = n >> 5, b = n & 31;
        const float v = acc[mt][nt][j] + bias[m];
        xw[(((size_t)dir * Tseg + tl) * G4_N + m) * B_N + b] = f2bfu(v);
      }
}

// ---------------------------------------------------------------------------
// Kernel 2: persistent recurrence, flag+bulk agent-scope (MALL) exchange.
// 64 wgs x 512 threads; dir = wg&1, cg = wg>>1. No XCD assumptions (G16-safe).
//   hx:  [dir][parity][cg=32][b=32][cl=16] bf16  (data, sc0 sc1)
//   flg: [dir][cg] u32, 64B-padded, monotonic value = steps completed.
// Per step: reduce prev lp (hides under wait) -> poll 1 flag/thread ->
// load own 64B slice -> LDS -> MFMA -> epilogue -> publish slice ->
// barrier (drains stores) -> tid0 flag store.
// Skew safety: a producer can't start overwriting parity slot P for step
// t+2 until all wgs flagged step t+1 done, which is after they consumed P.
// ---------------------------------------------------------------------------
__global__ __launch_bounds__(512, 1) void rec_kernel(
    const unsigned short* __restrict__ xw,
    const float* __restrict__ w_hh_f, const float* __restrict__ w_hh_b,
    const float* __restrict__ w_cls, const int* __restrict__ lengths,
    unsigned short* __restrict__ hx,         // [2][2][32][32][16] bf16
    unsigned int* __restrict__ flg,          // [2][32*16] u32
    float* __restrict__ c_buf,               // [2][B][H]
    float* __restrict__ lpart,               // [64 wg][B][T][2]
    int t0, int Tseg)
{
  __shared__ unsigned short Ah[32][520];   // 33.3 KB, row stride 1040B
  __shared__ float gate_p[8][32][17];      // K-half partials
  __shared__ float lp[16][33][2];          // logits partials

  const int tid = threadIdx.x;
  const int wg = blockIdx.x;
  const int dir = wg & 1;
  const int cg = wg >> 1;
  const int colbase = cg * 16;
  const float* __restrict__ w_hh = dir ? w_hh_b : w_hh_f;
  const int w = tid >> 6, lane = tid & 63;
  const int q = w >> 1, kh = w & 1;

  // one-time: W_hh fragments (gate q, K-half kh) into registers
  short8 wfrag[8];
  {
    const int grow = q * 512 + colbase + (lane & 15);
    const int kb = (lane >> 4) << 3;
    const float* __restrict__ wr_ = &w_hh[(size_t)grow * H_N + kh * 256];
#pragma unroll
    for (int ks = 0; ks < 8; ++ks) {
      const float4 f0 = *(const float4*)&wr_[ks * 32 + kb];
      const float4 f1 = *(const float4*)&wr_[ks * 32 + kb + 4];
      short8 v;
      v[0] = (short)f2bfu(f0.x); v[1] = (short)f2bfu(f0.y);
      v[2] = (short)f2bfu(f0.z); v[3] = (short)f2bfu(f0.w);
      v[4] = (short)f2bfu(f1.x); v[5] = (short)f2bfu(f1.y);
      v[6] = (short)f2bfu(f1.z); v[7] = (short)f2bfu(f1.w);
      wfrag[ks] = v;
    }
  }

  // per-thread epilogue ownership: b = tid>>4 (32), cl = tid&15 (16 cols)
  const int b = tid >> 4;
  const int cl = tid & 15;
  const int col = colbase + cl;
  const int Lb = lengths[b];
  const int Lb_r = lengths[tid & 31];      // for the tid<64 logits reducer
  float cc = c_buf[((size_t)dir * B_N + b) * H_N + col];
  const float wc0 = w_cls[dir * H_N + col];
  const float wc1 = w_cls[2 * H_N + dir * H_N + col];

  // initial h (own column) — plain load is safe: kernel-launch boundary is an
  // agent-scope acquire, so prior-dispatch sc1 stores are visible & caches fresh
  float hh = bfu2f(hx[((size_t)dir * 2 + (t0 & 1)) * 16384 + ((size_t)cg * 32 + b) * 16 + cl]);

  float* __restrict__ lslice = lpart + (size_t)wg * B_N * T_N * 2;
  unsigned int* __restrict__ myflag = flg + dir * 512 + cg * 16;
  unsigned int* __restrict__ pollflag = flg + dir * 512 + (tid >> 4) * 16;

  // prefetch step-0 xw gate values (plain cached loads)
  unsigned short xv[4];
  {
    const unsigned short* __restrict__ xb =
        &xw[((size_t)(dir * Tseg) * G4_N + colbase + cl) * B_N + b];
#pragma unroll
    for (int q2 = 0; q2 < 4; ++q2) xv[q2] = xb[(size_t)q2 * 512 * B_N];
  }

  for (int ts = 0; ts < Tseg; ++ts) {
    const int t = t0 + ts;

    // previous step's logits reduce FIRST — hides under the flag wait.
    // lp was completed before last step's barrier; nobody rewrites it until
    // the next epilogue (two barriers away). Safe.
    if (ts > 0 && tid < 64) {
      const int br = tid & 31, tau = tid >> 5;
      const int tp = t - 1;
      if (tp < Lb_r) {
        float s = 0.f;
#pragma unroll
        for (int k = 0; k < 16; ++k) s += lp[k][br][tau];
        const int tpos = dir ? (Lb_r - 1 - tp) : tp;
        lslice[((size_t)br * T_N + tpos) * 2 + tau] = s;
      }
    }

    // wait for the one producer whose slice this thread stages (cg' = tid>>4)
    {
      const unsigned int want = (unsigned int)t;
      while (__hip_atomic_load(pollflag, __ATOMIC_RELAXED, __HIP_MEMORY_SCOPE_AGENT) < want) {}
    }
    // bulk-load own 64B h slice (MALL) and place into Ah
    {
      const unsigned short* hsrc =
          hx + ((size_t)dir * 2 + (t & 1)) * 16384 + (size_t)tid * 32;
      uint32x4 va, vb, vc, vd;
      load64_mall(hsrc, va, vb, vc, vd);
      const int b0 = (tid & 15) * 2, cg16 = (tid >> 4) * 16;
      *(uint32x4*)&Ah[b0][cg16] = va;
      *(uint32x4*)&Ah[b0][cg16 + 8] = vb;
      *(uint32x4*)&Ah[b0 + 1][cg16] = vc;
      *(uint32x4*)&Ah[b0 + 1][cg16 + 8] = vd;
    }
    __syncthreads();  // SYNC1: Ah complete

    // MFMA: wave w computes gate q, K-half kh partials
    {
      f32x4 acc0 = {0.f, 0.f, 0.f, 0.f}, acc1 = {0.f, 0.f, 0.f, 0.f};
      const int kb = (lane >> 4) << 3;
#pragma unroll
      for (int ks = 0; ks < 8; ++ks) {
        const int kk = kh * 256 + (ks << 5) + kb;
        short8 a0 = *(const short8*)&Ah[(lane & 15)][kk];
        short8 a1 = *(const short8*)&Ah[16 + (lane & 15)][kk];
        acc0 = __builtin_amdgcn_mfma_f32_16x16x32_bf16(a0, wfrag[ks], acc0, 0, 0, 0);
        acc1 = __builtin_amdgcn_mfma_f32_16x16x32_bf16(a1, wfrag[ks], acc1, 0, 0, 0);
      }
      const int crow = (lane >> 4) << 2;
      const int ccol = lane & 15;
#pragma unroll
      for (int j = 0; j < 4; ++j) {
        gate_p[w][crow + j][ccol] = acc0[j];
        gate_p[w][16 + crow + j][ccol] = acc1[j];
      }
    }
    __syncthreads();  // SYNC2: gate_p ready

    // epilogue: merge K-halves, gates + state update (fp32)
    const bool valid = (t < Lb);
    float hn;
    {
      const float gi = gate_p[0][b][cl] + gate_p[1][b][cl] + bfu2f(xv[0]);
      const float gf = gate_p[2][b][cl] + gate_p[3][b][cl] + bfu2f(xv[1]);
      const float gg = gate_p[4][b][cl] + gate_p[5][b][cl] + bfu2f(xv[2]);
      const float go = gate_p[6][b][cl] + gate_p[7][b][cl] + bfu2f(xv[3]);
      const float cn = sigmf(gf) * cc + sigmf(gi) * tanhf(gg);
      hn = sigmf(go) * tanhf(cn);
      if (valid) { cc = cn; hh = hn; }
    }

    // publish h pair (MALL write-through); adjacent cols packed via shfl
    {
      const float hhp = __shfl_xor(hh, 1);
      if ((cl & 1) == 0) {
        const unsigned int pv =
            (unsigned int)f2bfu(hh) | ((unsigned int)f2bfu(hhp) << 16);
        store32_mall((unsigned int*)(hx + ((size_t)dir * 2 + ((t + 1) & 1)) * 16384 +
                                     ((size_t)cg * 32 + b) * 16 + cl),
                     pv);
      }
    }
    lp[cl][b][0] = valid ? hn * wc0 : 0.f;
    lp[cl][b][1] = valid ? hn * wc1 : 0.f;

    __syncthreads();  // SYNC3: compiler drains vmcnt(0) -> all slices at MALL
    if (tid == 0)
      __hip_atomic_store(myflag, (unsigned int)(t + 1),
                         __ATOMIC_RELAXED, __HIP_MEMORY_SCOPE_AGENT);

    // prefetch next step's xw (completes under next poll/MFMA)
    if (ts + 1 < Tseg) {
      const unsigned short* __restrict__ xb =
          &xw[((size_t)(dir * Tseg + ts + 1) * G4_N + colbase + cl) * B_N + b];
#pragma unroll
      for (int q2 = 0; q2 < 4; ++q2) xv[q2] = xb[(size_t)q2 * 512 * B_N];
    }
  }

  // final step's logits reduce
  if (tid < 64) {
    const int br = tid & 31, tau = tid >> 5;
    const int tp = t0 + Tseg - 1;
    if (tp < Lb_r) {
      float s = 0.f;
#pragma unroll
      for (int k = 0; k < 16; ++k) s += lp[k][br][tau];
      const int tpos = dir ? (Lb_r - 1 - tp) : tp;
      lslice[((size_t)br * T_N + tpos) * 2 + tau] = s;
    }
  }

  // persist c across segment launches (h persists via hx)
  c_buf[((size_t)dir * B_N + b) * H_N + col] = cc;
}

// ---------------------------------------------------------------------------
__global__ void init_kernel(ull* __restrict__ hx64, float* __restrict__ c_buf,
                            unsigned int* __restrict__ flg)
{
  const int i = blockIdx.x * 256 + threadIdx.x;  // 0..65535
  if (i < 16384) hx64[i] = 0ull;                 // hx: 128 KB of zeros
  if (i < 2 * B_N * H_N) c_buf[i] = 0.f;
  if (i < 1024) flg[i] = 0u;
}

__global__ void reduce_softmax_kernel(const float* __restrict__ lpart,
                                      const float* __restrict__ b_cls,
                                      float* __restrict__ out)
{
  const int i = blockIdx.x * 256 + threadIdx.x;  // 0..32767
  if (i >= B_N * T_N) return;
  float s0 = b_cls[0], s1 = b_cls[1];
  const float* __restrict__ p = lpart + (size_t)i * 2;
#pragma unroll 8
  for (int wg = 0; wg < 64; ++wg) {
    s0 += p[(size_t)wg * B_N * T_N * 2];
    s1 += p[(size_t)wg * B_N * T_N * 2 + 1];
  }
  const float m = fmaxf(s0, s1);
  const float e0 = expf(s0 - m), e1 = expf(s1 - m);
  const float inv = 1.f / (e0 + e1);
  out[2 * i] = e0 * inv;
  out[2 * i + 1] = e1 * inv;
}

// ---------------------------------------------------------------------------
extern "C" void kernel_launch(void* const* d_in, const int* in_sizes, int n_in,
                              void* d_out, int out_size, void* d_ws, size_t ws_size,
                              hipStream_t stream)
{
  const float* xs      = (const float*)d_in[0];
  const int*   lengths = (const int*)d_in[1];
  const float* w_ih_f  = (const float*)d_in[3];
  const float* w_hh_f  = (const float*)d_in[4];
  const float* b_f     = (const float*)d_in[5];
  const float* w_ih_b  = (const float*)d_in[6];
  const float* w_hh_b  = (const float*)d_in[7];
  const float* b_b     = (const float*)d_in[8];
  const float* w_cls   = (const float*)d_in[9];
  const float* b_cls   = (const float*)d_in[10];
  float* out = (float*)d_out;

  auto alignup = [](size_t v) { return (v + 255) & ~(size_t)255; };
  const size_t hx_b    = alignup((size_t)2 * 2 * 32 * 32 * 16 * 2);   // 128 KB
  const size_t flg_b   = alignup((size_t)1024 * 4);                   // 4 KB
  const size_t cbuf_b  = alignup((size_t)2 * B_N * H_N * 4);          // 128 KB
  const size_t lpart_b = alignup((size_t)64 * B_N * T_N * 2 * 4);     // 16 MB
  const size_t fixed = hx_b + flg_b + cbuf_b + lpart_b + 1024;

  int nseg = 1;
  while (nseg < 64) {
    const size_t xwb = alignup((size_t)2 * (T_N / nseg) * G4_N * B_N * 2);
    if (xwb + fixed <= ws_size) break;
    nseg <<= 1;
  }
  const int Tseg = T_N / nseg;
  const size_t xw_b = alignup((size_t)2 * Tseg * G4_N * B_N * 2);

  char* p = (char*)d_ws;
  unsigned short* xw = (unsigned short*)p;  p += xw_b;
  unsigned short* hx = (unsigned short*)p;  p += hx_b;
  unsigned int* flg = (unsigned int*)p;     p += flg_b;
  float* c_buf = (float*)p;                 p += cbuf_b;
  float* lpart = (float*)p;                 p += lpart_b;

  hipMemsetAsync(lpart, 0, lpart_b, stream);
  init_kernel<<<256, 256, 0, stream>>>((ull*)hx, c_buf, flg);

  for (int s = 0; s < nseg; ++s) {
    const int t0 = s * Tseg;
    dim3 g(G4_N / 64, (Tseg * B_N) / 64, 2);
    xw_gemm_kernel<<<g, 256, 0, stream>>>(xs, lengths, w_ih_f, b_f, w_ih_b, b_b, xw, t0, Tseg);
    rec_kernel<<<64, 512, 0, stream>>>(xw, w_hh_f, w_hh_b, w_cls, lengths,
                                       hx, flg, c_buf, lpart, t0, Tseg);
  }

  reduce_softmax_kernel<<<128, 256, 0, stream>>>(lpart, b_cls, out);
}